// Round 11
// baseline (494.746 us; speedup 1.0000x reference)
//
#include <hip/hip_runtime.h>

#define HH 256
#define KK 8

typedef __attribute__((ext_vector_type(8))) short s16x8;
typedef __attribute__((ext_vector_type(4))) float f32x4;

__device__ __forceinline__ float bf2f(unsigned short u){ unsigned x=((unsigned)u)<<16; return __builtin_bit_cast(float,x); }
__device__ __forceinline__ unsigned short f2bf(float f){ unsigned x=__builtin_bit_cast(unsigned,f); return (unsigned short)((x+0x7fffu+((x>>16)&1u))>>16); }
__device__ __forceinline__ float sigmoidf(float x){ return __builtin_amdgcn_rcpf(1.0f + __expf(-x)); }

// ---- K1: all 4 weights f32 -> bf16.  grid (32,4) x 256thr ----
__global__ void cvt_w(const float* __restrict__ wa, const float* __restrict__ wu,
                      const float* __restrict__ wv, const float* __restrict__ wbm,
                      unsigned short* __restrict__ dst){
  const int w = blockIdx.y;
  const float* src = (w==0)? wa : (w==1)? wu : (w==2)? wv : wbm;
  const int i = blockIdx.x*256 + threadIdx.x;
  const float4* s = reinterpret_cast<const float4*>(src);
  float4 a = s[i*2], b = s[i*2+1];
  uint4 o;
  o.x = (unsigned)f2bf(a.x) | ((unsigned)f2bf(a.y)<<16);
  o.y = (unsigned)f2bf(a.z) | ((unsigned)f2bf(a.w)<<16);
  o.z = (unsigned)f2bf(b.x) | ((unsigned)f2bf(b.y)<<16);
  o.w = (unsigned)f2bf(b.z) | ((unsigned)f2bf(b.w)<<16);
  reinterpret_cast<uint4*>(dst + (size_t)w*65536)[i] = o;
}

// ---- K2: px[m][1024] = prev[m,:] @ [W_A|W_U|W_V|W_B]^T ----
// B-frags RESIDENT in registers (64 VGPR/wave = 32 out-cols x K=256).
// 1024 thr / 16 waves; grid (128, 2) = 256 blocks = 1/CU. No barriers.
// Rows streamed in 16-row chunks; all 16 waves read the same rows (L1 hit).
// px stores via wave-private swizzled LDS bounce -> 64B-segment uint4 stores.
__global__ __launch_bounds__(1024, 4)
void gemm_breg(const float* __restrict__ prev,
               const unsigned short* __restrict__ wb,   // [1024][256] bf16 rows = out-cols
               unsigned short* __restrict__ px,         // [N][1024] bf16
               int n, int rpb)
{
  __shared__ unsigned short scratch[16*512];   // 16 waves x (16 rows x 32 cols) = 16KB
  const int tid  = threadIdx.x;
  const int lane = tid & 63, wid = tid >> 6;
  const int lm   = lane & 15, kc = lane >> 4;
  const int colbase = blockIdx.y * 512 + wid * 32;

  // ---- B-fragments: resident for the whole kernel (L2-hot source) ----
  s16x8 b[2][8];
  #pragma unroll
  for (int cg=0; cg<2; ++cg){
    const char* bp = reinterpret_cast<const char*>(wb)
                   + (size_t)(colbase + cg*16 + lm)*512 + kc*16;
    #pragma unroll
    for (int kk=0; kk<8; ++kk)
      b[cg][kk] = *reinterpret_cast<const s16x8*>(bp + kk*64);
  }

  unsigned short* sw = scratch + wid*512;      // wave-private bounce
  const int r0blk = blockIdx.x * rpb;
  const int rend  = min(r0blk + rpb, n);
  const int rrow  = lane >> 2, part = lane & 3;
  const int rgrp  = part ^ (rrow >> 2);        // un-swizzle group for readback

  for (int r0 = r0blk; r0 < rend; r0 += 16){
    const int arow = r0 + lm;
    const char* rp = reinterpret_cast<const char*>(prev + (size_t)min(arow, n-1) * HH);

    f32x4 acc[2];
    acc[0] = (f32x4){0.f,0.f,0.f,0.f};
    acc[1] = (f32x4){0.f,0.f,0.f,0.f};

    #pragma unroll
    for (int h=0; h<2; ++h){
      s16x8 af[4];
      #pragma unroll
      for (int k4=0; k4<4; ++k4){
        const int kk = h*4 + k4;
        float4 f0 = *reinterpret_cast<const float4*>(rp + kk*128 + kc*32);
        float4 f1 = *reinterpret_cast<const float4*>(rp + kk*128 + kc*32 + 16);
        s16x8 a;
        a[0]=(short)f2bf(f0.x); a[1]=(short)f2bf(f0.y);
        a[2]=(short)f2bf(f0.z); a[3]=(short)f2bf(f0.w);
        a[4]=(short)f2bf(f1.x); a[5]=(short)f2bf(f1.y);
        a[6]=(short)f2bf(f1.z); a[7]=(short)f2bf(f1.w);
        af[k4] = a;
      }
      #pragma unroll
      for (int k4=0; k4<4; ++k4){
        acc[0] = __builtin_amdgcn_mfma_f32_16x16x32_bf16(af[k4], b[0][h*4+k4], acc[0], 0, 0, 0);
        acc[1] = __builtin_amdgcn_mfma_f32_16x16x32_bf16(af[k4], b[1][h*4+k4], acc[1], 0, 0, 0);
      }
    }

    // ---- wave-private bounce (no barrier): write swizzled, read b128 ----
    // D: col=lane&15, row=(lane>>4)*4+reg.  col-index XOR (kc<<3) per row-quad.
    #pragma unroll
    for (int cg=0; cg<2; ++cg)
      #pragma unroll
      for (int r=0; r<4; ++r)
        sw[(kc*4 + r)*32 + ((cg*16 + lm) ^ (kc<<3))] = f2bf(acc[cg][r]);

    // readback: row=lane>>2, 8-short group (part ^ (row>>2)) -> cols part*8..+7
    uint4 v = *reinterpret_cast<const uint4*>(sw + rrow*32 + rgrp*8);
    const int gr = r0 + rrow;
    if (gr < n)
      *reinterpret_cast<uint4*>(px + (size_t)gr*1024 + colbase + part*8) = v;
  }
}

// ---- K3: gather epilogue. 64 lanes per node, 4 cols/lane; fat loads/stores. ----
__global__ __launch_bounds__(256)
void epilogue(const unsigned short* __restrict__ px,   // [N][4][256]: A,U,V,B
              const int* __restrict__ parent,
              const int* __restrict__ child,
              const int* __restrict__ mask,
              float* __restrict__ out,
              int n)
{
  const int e = blockIdx.x*4 + (threadIdx.x>>6);   // wave-uniform node
  if (e >= n) return;
  const int c4 = (threadIdx.x & 63) * 4;
  const int p  = parent[e];

  const unsigned short* rp = px + (size_t)p*1024 + c4;
  uint2 av = *reinterpret_cast<const uint2*>(rp);         // PA (4 bf16)
  uint2 uv = *reinterpret_cast<const uint2*>(rp + 256);   // PU
  const unsigned short* ap = reinterpret_cast<const unsigned short*>(&av);
  const unsigned short* up = reinterpret_cast<const unsigned short*>(&uv);

  float A[4], o[4], eta[4];
  #pragma unroll
  for (int j=0;j<4;++j){ A[j]=bf2f(ap[j]); o[j]=bf2f(up[j]); eta[j]=0.f; }

  int nm = 0;
  #pragma unroll
  for (int k=0;k<KK;++k){
    if (mask[(size_t)e*KK + k]){
      const unsigned short* rc = px + (size_t)child[(size_t)e*KK + k]*1024 + c4;
      uint2 pv = *reinterpret_cast<const uint2*>(rc + 512);   // PV
      uint2 pb = *reinterpret_cast<const uint2*>(rc + 768);   // PB
      const unsigned short* vp = reinterpret_cast<const unsigned short*>(&pv);
      const unsigned short* bp = reinterpret_cast<const unsigned short*>(&pb);
      #pragma unroll
      for (int j=0;j<4;++j){
        o[j]   += bf2f(vp[j]);
        eta[j] += sigmoidf(A[j] + bf2f(bp[j]));
      }
    } else ++nm;
  }

  const float fnm = (float)nm;
  float4 r;
  {
    float v0 = o[0] + eta[0] + fnm*sigmoidf(A[0]);
    float v1 = o[1] + eta[1] + fnm*sigmoidf(A[1]);
    float v2 = o[2] + eta[2] + fnm*sigmoidf(A[2]);
    float v3 = o[3] + eta[3] + fnm*sigmoidf(A[3]);
    r.x = v0>0.f?v0:0.f; r.y = v1>0.f?v1:0.f;
    r.z = v2>0.f?v2:0.f; r.w = v3>0.f?v3:0.f;
  }
  *reinterpret_cast<float4*>(out + (size_t)p*HH + c4) = r;
}

extern "C" void kernel_launch(void* const* d_in, const int* in_sizes, int n_in,
                              void* d_out, int out_size, void* d_ws, size_t ws_size,
                              hipStream_t stream)
{
  const float* prev = (const float*)d_in[0];
  const float* W_U  = (const float*)d_in[1];
  const float* W_V  = (const float*)d_in[2];
  const float* W_A  = (const float*)d_in[3];
  const float* W_B  = (const float*)d_in[4];
  const int* parent = (const int*)d_in[5];
  const int* child  = (const int*)d_in[6];
  const int* mask   = (const int*)d_in[7];
  float* out = (float*)d_out;

  const int n_nodes = in_sizes[5];

  unsigned short* wb = (unsigned short*)d_ws;      // [1024][256] bf16 (A,U,V,B rows)
  unsigned short* px = wb + 4*65536;               // [N][1024] bf16

  dim3 gc(32, 4);
  cvt_w<<<gc, 256, 0, stream>>>(W_A, W_U, W_V, W_B, wb);

  // rows per block: ceil(n/128) rounded up to a multiple of 16
  const int rpb = ((n_nodes + 127)/128 + 15) & ~15;
  dim3 g2(128, 2);
  gemm_breg<<<g2, 1024, 0, stream>>>(prev, wb, px, n_nodes, rpb);

  epilogue<<<(n_nodes + 3)/4, 256, 0, stream>>>(px, parent, child, mask, out, n_nodes);
}

// Round 12
// 296.436 us; speedup vs baseline: 1.6690x; 1.6690x over previous
//
#include <hip/hip_runtime.h>

#define HH 256
#define KK 8

typedef __attribute__((ext_vector_type(8))) short s16x8;
typedef __attribute__((ext_vector_type(4))) float f32x4;

__device__ __forceinline__ float bf2f(unsigned short u){ unsigned x=((unsigned)u)<<16; return __builtin_bit_cast(float,x); }
__device__ __forceinline__ unsigned f2bf(float f){ unsigned x=__builtin_bit_cast(unsigned,f); return (x+0x7fffu+((x>>16)&1u))>>16; }
__device__ __forceinline__ float sigmoidf(float x){ return __builtin_amdgcn_rcpf(1.0f + __expf(-x)); }

// ---- K1: weights f32 -> bf16 in MFMA-fragment order ----
// wf chunk t (16B) = 8 bf16: W_w[col][k0..k0+8) where
//   w=t>>13, cgl=(t>>9)&15, kk=(t>>6)&7, ln=t&63, col=cgl*16+(ln&15), k0=kk*32+(ln>>4)*8
// so a wave's b-frag (cg,kk) load is base + lane*16 : fully coalesced 1KB.
__global__ void cvt_w_frag(const float* __restrict__ wa, const float* __restrict__ wu,
                           const float* __restrict__ wv, const float* __restrict__ wbm,
                           unsigned short* __restrict__ wf){
  const int t = blockIdx.x*256 + threadIdx.x;        // 32768 total
  const int w = t >> 13;
  const float* src = (w==0)? wa : (w==1)? wu : (w==2)? wv : wbm;
  const int rem = t & 8191;
  const int cgl = rem >> 9;
  const int r2  = rem & 511;
  const int kk  = r2 >> 6;
  const int ln  = r2 & 63;
  const int col = cgl*16 + (ln & 15);
  const int k0  = kk*32 + (ln >> 4)*8;
  const float4* s = reinterpret_cast<const float4*>(src + col*HH + k0);
  float4 f0 = s[0], f1 = s[1];
  uint4 o;
  o.x = f2bf(f0.x) | (f2bf(f0.y)<<16);
  o.y = f2bf(f0.z) | (f2bf(f0.w)<<16);
  o.z = f2bf(f1.x) | (f2bf(f1.y)<<16);
  o.w = f2bf(f1.z) | (f2bf(f1.w)<<16);
  reinterpret_cast<uint4*>(wf)[t] = o;
}

// ---- K2: px[m][1024] = prev[m,:] @ [W_A|W_U|W_V|W_B]^T ----
// Barrier-free, LDS-free. 256 thr / 4 waves; wave owns 32 rows with A-frags
// RESIDENT (64 VGPR). Streams 64 col-groups; B-frags are 1KB coalesced L2
// loads in fragment order. waves_per_eu(2,4) stops the 64-VGPR spill heuristic.
__global__ __launch_bounds__(256)
__attribute__((amdgpu_waves_per_eu(2, 4)))
void gemm_frag(const float* __restrict__ prev,
               const unsigned short* __restrict__ wf,   // fragment-order weights
               unsigned short* __restrict__ px,         // [N][1024] bf16
               int n)
{
  const int lane = threadIdx.x & 63, wid = threadIdx.x >> 6;
  const int r0   = blockIdx.x * 128 + wid * 32;
  const int lm   = lane & 15, kc = lane >> 4;

  // ---- A fragments (resident): rows r0+lm and r0+16+lm, k = kk*32+kc*8.. ----
  s16x8 af0[8], af1[8];
  {
    const int row = min(r0 + lm, n-1);
    const char* rp = reinterpret_cast<const char*>(prev + (size_t)row * HH);
    #pragma unroll
    for (int kk=0; kk<8; ++kk){
      float4 f0 = *reinterpret_cast<const float4*>(rp + kk*128 + kc*32);
      float4 f1 = *reinterpret_cast<const float4*>(rp + kk*128 + kc*32 + 16);
      s16x8 a;
      a[0]=(short)f2bf(f0.x); a[1]=(short)f2bf(f0.y);
      a[2]=(short)f2bf(f0.z); a[3]=(short)f2bf(f0.w);
      a[4]=(short)f2bf(f1.x); a[5]=(short)f2bf(f1.y);
      a[6]=(short)f2bf(f1.z); a[7]=(short)f2bf(f1.w);
      af0[kk] = a;
    }
  }
  {
    const int row = min(r0 + 16 + lm, n-1);
    const char* rp = reinterpret_cast<const char*>(prev + (size_t)row * HH);
    #pragma unroll
    for (int kk=0; kk<8; ++kk){
      float4 f0 = *reinterpret_cast<const float4*>(rp + kk*128 + kc*32);
      float4 f1 = *reinterpret_cast<const float4*>(rp + kk*128 + kc*32 + 16);
      s16x8 a;
      a[0]=(short)f2bf(f0.x); a[1]=(short)f2bf(f0.y);
      a[2]=(short)f2bf(f0.z); a[3]=(short)f2bf(f0.w);
      a[4]=(short)f2bf(f1.x); a[5]=(short)f2bf(f1.y);
      a[6]=(short)f2bf(f1.z); a[7]=(short)f2bf(f1.w);
      af1[kk] = a;
    }
  }

  // ---- stream 64 col-groups; 8 coalesced b-loads + 16 MFMA each ----
  const char* wfc = reinterpret_cast<const char*>(wf) + lane*16;
  for (int cg=0; cg<64; ++cg){
    const char* bp = wfc + cg*8192;
    f32x4 acc0 = {0.f,0.f,0.f,0.f}, acc1 = {0.f,0.f,0.f,0.f};
    #pragma unroll
    for (int kk=0; kk<8; ++kk){
      s16x8 b = *reinterpret_cast<const s16x8*>(bp + kk*1024);
      acc0 = __builtin_amdgcn_mfma_f32_16x16x32_bf16(af0[kk], b, acc0, 0, 0, 0);
      acc1 = __builtin_amdgcn_mfma_f32_16x16x32_bf16(af1[kk], b, acc1, 0, 0, 0);
    }
    // D: col=lane&15, row=(lane>>4)*4+reg
    #pragma unroll
    for (int r=0; r<4; ++r){
      const int row0 = r0 + kc*4 + r;
      if (row0 < n) px[(size_t)row0*1024 + cg*16 + lm] = (unsigned short)f2bf(acc0[r]);
      const int row1 = row0 + 16;
      if (row1 < n) px[(size_t)row1*1024 + cg*16 + lm] = (unsigned short)f2bf(acc1[r]);
    }
  }
}

// ---- K3: gather epilogue. 64 lanes per node, 4 cols/lane; fat loads/stores. ----
__global__ __launch_bounds__(256)
void epilogue(const unsigned short* __restrict__ px,   // [N][4][256]: A,U,V,B
              const int* __restrict__ parent,
              const int* __restrict__ child,
              const int* __restrict__ mask,
              float* __restrict__ out,
              int n)
{
  const int e = blockIdx.x*4 + (threadIdx.x>>6);   // wave-uniform node
  if (e >= n) return;
  const int c4 = (threadIdx.x & 63) * 4;
  const int p  = parent[e];

  const unsigned short* rp = px + (size_t)p*1024 + c4;
  uint2 av = *reinterpret_cast<const uint2*>(rp);         // PA (4 bf16)
  uint2 uv = *reinterpret_cast<const uint2*>(rp + 256);   // PU
  const unsigned short* ap = reinterpret_cast<const unsigned short*>(&av);
  const unsigned short* up = reinterpret_cast<const unsigned short*>(&uv);

  float A[4], o[4], eta[4];
  #pragma unroll
  for (int j=0;j<4;++j){ A[j]=bf2f(ap[j]); o[j]=bf2f(up[j]); eta[j]=0.f; }

  int nm = 0;
  #pragma unroll
  for (int k=0;k<KK;++k){
    if (mask[(size_t)e*KK + k]){
      const unsigned short* rc = px + (size_t)child[(size_t)e*KK + k]*1024 + c4;
      uint2 pv = *reinterpret_cast<const uint2*>(rc + 512);   // PV
      uint2 pb = *reinterpret_cast<const uint2*>(rc + 768);   // PB
      const unsigned short* vp = reinterpret_cast<const unsigned short*>(&pv);
      const unsigned short* bp = reinterpret_cast<const unsigned short*>(&pb);
      #pragma unroll
      for (int j=0;j<4;++j){
        o[j]   += bf2f(vp[j]);
        eta[j] += sigmoidf(A[j] + bf2f(bp[j]));
      }
    } else ++nm;
  }

  const float fnm = (float)nm;
  float4 r;
  {
    float v0 = o[0] + eta[0] + fnm*sigmoidf(A[0]);
    float v1 = o[1] + eta[1] + fnm*sigmoidf(A[1]);
    float v2 = o[2] + eta[2] + fnm*sigmoidf(A[2]);
    float v3 = o[3] + eta[3] + fnm*sigmoidf(A[3]);
    r.x = v0>0.f?v0:0.f; r.y = v1>0.f?v1:0.f;
    r.z = v2>0.f?v2:0.f; r.w = v3>0.f?v3:0.f;
  }
  *reinterpret_cast<float4*>(out + (size_t)p*HH + c4) = r;
}

extern "C" void kernel_launch(void* const* d_in, const int* in_sizes, int n_in,
                              void* d_out, int out_size, void* d_ws, size_t ws_size,
                              hipStream_t stream)
{
  const float* prev = (const float*)d_in[0];
  const float* W_U  = (const float*)d_in[1];
  const float* W_V  = (const float*)d_in[2];
  const float* W_A  = (const float*)d_in[3];
  const float* W_B  = (const float*)d_in[4];
  const int* parent = (const int*)d_in[5];
  const int* child  = (const int*)d_in[6];
  const int* mask   = (const int*)d_in[7];
  float* out = (float*)d_out;

  const int n_nodes = in_sizes[5];

  unsigned short* wf = (unsigned short*)d_ws;      // fragment-order weights, 512KB
  unsigned short* px = wf + 4*65536;               // [N][1024] bf16

  cvt_w_frag<<<128, 256, 0, stream>>>(W_A, W_U, W_V, W_B, wf);

  gemm_frag<<<(n_nodes + 127)/128, 256, 0, stream>>>(prev, wf, px, n_nodes);

  epilogue<<<(n_nodes + 3)/4, 256, 0, stream>>>(px, parent, child, mask, out, n_nodes);
}

// Round 13
// 227.409 us; speedup vs baseline: 2.1756x; 1.3035x over previous
//
#include <hip/hip_runtime.h>

#define HH 256
#define KK 8

typedef __attribute__((ext_vector_type(8))) short s16x8;
typedef __attribute__((ext_vector_type(4))) float f32x4;

__device__ __forceinline__ float bf2f(unsigned short u){ unsigned x=((unsigned)u)<<16; return __builtin_bit_cast(float,x); }
__device__ __forceinline__ unsigned f2bf(float f){ unsigned x=__builtin_bit_cast(unsigned,f); return (x+0x7fffu+((x>>16)&1u))>>16; }
__device__ __forceinline__ float sigmoidf(float x){ return __builtin_amdgcn_rcpf(1.0f + __expf(-x)); }

// ---- K1: all 4 weights f32 -> bf16.  grid (32,4) x 256thr ----
__global__ void cvt_w(const float* __restrict__ wa, const float* __restrict__ wu,
                      const float* __restrict__ wv, const float* __restrict__ wbm,
                      unsigned short* __restrict__ dst){
  const int w = blockIdx.y;
  const float* src = (w==0)? wa : (w==1)? wu : (w==2)? wv : wbm;
  const int i = blockIdx.x*256 + threadIdx.x;
  const float4* s = reinterpret_cast<const float4*>(src);
  float4 a = s[i*2], b = s[i*2+1];
  uint4 o;
  o.x = f2bf(a.x) | (f2bf(a.y)<<16);
  o.y = f2bf(a.z) | (f2bf(a.w)<<16);
  o.z = f2bf(b.x) | (f2bf(b.y)<<16);
  o.w = f2bf(b.z) | (f2bf(b.w)<<16);
  reinterpret_cast<uint4*>(dst + (size_t)w*65536)[i] = o;
}

// ---- K2: px[m][1024] = prev[m,:] @ [W_A|W_U|W_V|W_B]^T ----
// 512 thr / 8 waves; block = 128 rows x 1024 cols. As (64KB) + Bs panel (16KB).
// Raw barriers (no vmcnt drain) + 2-deep register prefetch of B panels.
__global__ __launch_bounds__(512, 2)
void gemm_all(const float* __restrict__ prev,
              const unsigned short* __restrict__ wb,   // [1024][256] bf16 rows = out-cols
              unsigned short* __restrict__ px,         // [N][1024] bf16
              int n)
{
  __shared__ char smem[81920];          // As 64KB + Bs 16KB
  char* bs = smem + 65536;
  const int tid = threadIdx.x;
  const int m0  = blockIdx.x * 128;
  const int lane = tid & 63, wid = tid >> 6;
  const int wr = wid >> 1, wc = wid & 1;   // 4 row-groups(32) x 2 col-halves(64)
  const int lm = lane & 15, kc = lane >> 4;
  const int srow0 = tid >> 3, sch = tid & 7;          // B staging coords
  const char* wbc = reinterpret_cast<const char*>(wb);

  // prologue: issue panels 0,1 into regs (L2 latency hides under As staging)
  uint4 P0a, P0b, P1a, P1b;
  {
    const char* g0 = wbc + srow0*512 + sch*16;                 // panel 0 (g=0,ks=0)
    P0a = *reinterpret_cast<const uint4*>(g0);
    P0b = *reinterpret_cast<const uint4*>(g0 + 32768);
    const char* g1 = wbc + 128 + srow0*512 + sch*16;           // panel 1 (g=0,ks=1)
    P1a = *reinterpret_cast<const uint4*>(g1);
    P1b = *reinterpret_cast<const uint4*>(g1 + 32768);
  }

  // ---- stage A-tile: 128 rows x 256k, f32->bf16, swizzled ----
  #pragma unroll
  for (int it=0; it<8; ++it){
    const int c = it*512 + tid;
    const int row = c>>5, kch = c&31;
    const int gm = m0 + row;
    uint4 o = {0u,0u,0u,0u};
    if (gm < n){
      const float4* sp = reinterpret_cast<const float4*>(prev + (size_t)gm*HH + kch*8);
      float4 f0 = sp[0], f1 = sp[1];
      o.x=f2bf(f0.x)|(f2bf(f0.y)<<16);
      o.y=f2bf(f0.z)|(f2bf(f0.w)<<16);
      o.z=f2bf(f1.x)|(f2bf(f1.y)<<16);
      o.w=f2bf(f1.z)|(f2bf(f1.w)<<16);
    }
    *reinterpret_cast<uint4*>(smem + row*512 + ((kch*16) ^ ((row&7)<<4))) = o;
  }
  __syncthreads();      // one full drain, once per block

  f32x4 acc[2][4];

  // panel q = g*4 + ks: cols [g*128,+128), k [ks*64,+64). Bs row=col (128B), swizzled.
  #define STEP(q_, Pa, Pb)                                                        \
  {                                                                               \
    __builtin_amdgcn_s_barrier();          /* prev-panel readers done */          \
    { const int swb = (srow0&7)<<4;                                               \
      *reinterpret_cast<uint4*>(bs + srow0*128 + ((sch*16) ^ swb)) = Pa;          \
      *reinterpret_cast<uint4*>(bs + (srow0+64)*128 + ((sch*16) ^ swb)) = Pb; }   \
    asm volatile("s_waitcnt lgkmcnt(0)" ::: "memory");                            \
    __builtin_amdgcn_s_barrier();          /* panel visible */                    \
    __builtin_amdgcn_sched_barrier(0);                                            \
    if ((q_) + 2 < 32){                                                           \
      const int p2_ = (q_) + 2;                                                   \
      const char* gb_ = wbc + (p2_>>2)*65536 + (p2_&3)*128 + srow0*512 + sch*16;  \
      Pa = *reinterpret_cast<const uint4*>(gb_);                                  \
      Pb = *reinterpret_cast<const uint4*>(gb_ + 32768);                          \
    }                                                                             \
    const int ks_ = (q_)&3, g_ = (q_)>>2;                                         \
    if (ks_==0){                                                                  \
      _Pragma("unroll")                                                           \
      for (int i_=0;i_<2;++i_){ _Pragma("unroll")                                 \
        for (int j_=0;j_<4;++j_) acc[i_][j_]=(f32x4){0.f,0.f,0.f,0.f}; }          \
    }                                                                             \
    __builtin_amdgcn_s_setprio(1);                                                \
    _Pragma("unroll")                                                             \
    for (int kk_=0; kk_<2; ++kk_){                                                \
      s16x8 a0_, a1_;                                                             \
      { const int row_ = wr*32 + lm;                                              \
        a0_ = *reinterpret_cast<const s16x8*>(smem + row_*512                     \
              + ((ks_*128 + kk_*64 + kc*16) ^ ((row_&7)<<4))); }                  \
      { const int row_ = wr*32 + 16 + lm;                                         \
        a1_ = *reinterpret_cast<const s16x8*>(smem + row_*512                     \
              + ((ks_*128 + kk_*64 + kc*16) ^ ((row_&7)<<4))); }                  \
      _Pragma("unroll")                                                           \
      for (int j_=0;j_<4;++j_){                                                   \
        const int brow_ = wc*64 + j_*16 + lm;                                     \
        s16x8 b_ = *reinterpret_cast<const s16x8*>(bs + brow_*128                 \
              + ((kk_*64 + kc*16) ^ ((brow_&7)<<4)));                             \
        acc[0][j_] = __builtin_amdgcn_mfma_f32_16x16x32_bf16(a0_, b_, acc[0][j_], 0,0,0); \
        acc[1][j_] = __builtin_amdgcn_mfma_f32_16x16x32_bf16(a1_, b_, acc[1][j_], 0,0,0); \
      }                                                                           \
    }                                                                             \
    __builtin_amdgcn_s_setprio(0);                                                \
    if (ks_==3){                                                                  \
      _Pragma("unroll")                                                           \
      for (int i_=0;i_<2;++i_){ _Pragma("unroll")                                 \
        for (int r_=0;r_<4;++r_){                                                 \
          const int gm_ = m0 + wr*32 + i_*16 + kc*4 + r_;                         \
          if (gm_ < n){                                                           \
            unsigned short* dp_ = px + (size_t)gm_*1024 + g_*128 + wc*64 + lm;    \
            _Pragma("unroll")                                                     \
            for (int j_=0;j_<4;++j_) dp_[j_*16] = (unsigned short)f2bf(acc[i_][j_][r_]); \
          } } }                                                                   \
    }                                                                             \
  }

  #pragma unroll
  for (int qq=0; qq<16; ++qq){
    STEP(qq*2,   P0a, P0b)
    STEP(qq*2+1, P1a, P1b)
  }
  #undef STEP
}

// ---- K3: gather epilogue. 64 lanes per node, 4 cols/lane; fat loads/stores. ----
__global__ __launch_bounds__(256)
void epilogue(const unsigned short* __restrict__ px,   // [N][4][256]: A,U,V,B
              const int* __restrict__ parent,
              const int* __restrict__ child,
              const int* __restrict__ mask,
              float* __restrict__ out,
              int n)
{
  const int e = blockIdx.x*4 + (threadIdx.x>>6);   // wave-uniform node
  if (e >= n) return;
  const int c4 = (threadIdx.x & 63) * 4;
  const int p  = parent[e];

  const unsigned short* rp = px + (size_t)p*1024 + c4;
  uint2 av = *reinterpret_cast<const uint2*>(rp);         // PA (4 bf16)
  uint2 uv = *reinterpret_cast<const uint2*>(rp + 256);   // PU
  const unsigned short* ap = reinterpret_cast<const unsigned short*>(&av);
  const unsigned short* up = reinterpret_cast<const unsigned short*>(&uv);

  float A[4], o[4], eta[4];
  #pragma unroll
  for (int j=0;j<4;++j){ A[j]=bf2f(ap[j]); o[j]=bf2f(up[j]); eta[j]=0.f; }

  int nm = 0;
  #pragma unroll
  for (int k=0;k<KK;++k){
    if (mask[(size_t)e*KK + k]){
      const unsigned short* rc = px + (size_t)child[(size_t)e*KK + k]*1024 + c4;
      uint2 pv = *reinterpret_cast<const uint2*>(rc + 512);   // PV
      uint2 pb = *reinterpret_cast<const uint2*>(rc + 768);   // PB
      const unsigned short* vp = reinterpret_cast<const unsigned short*>(&pv);
      const unsigned short* bp = reinterpret_cast<const unsigned short*>(&pb);
      #pragma unroll
      for (int j=0;j<4;++j){
        o[j]   += bf2f(vp[j]);
        eta[j] += sigmoidf(A[j] + bf2f(bp[j]));
      }
    } else ++nm;
  }

  const float fnm = (float)nm;
  float4 r;
  {
    float v0 = o[0] + eta[0] + fnm*sigmoidf(A[0]);
    float v1 = o[1] + eta[1] + fnm*sigmoidf(A[1]);
    float v2 = o[2] + eta[2] + fnm*sigmoidf(A[2]);
    float v3 = o[3] + eta[3] + fnm*sigmoidf(A[3]);
    r.x = v0>0.f?v0:0.f; r.y = v1>0.f?v1:0.f;
    r.z = v2>0.f?v2:0.f; r.w = v3>0.f?v3:0.f;
  }
  *reinterpret_cast<float4*>(out + (size_t)p*HH + c4) = r;
}

extern "C" void kernel_launch(void* const* d_in, const int* in_sizes, int n_in,
                              void* d_out, int out_size, void* d_ws, size_t ws_size,
                              hipStream_t stream)
{
  const float* prev = (const float*)d_in[0];
  const float* W_U  = (const float*)d_in[1];
  const float* W_V  = (const float*)d_in[2];
  const float* W_A  = (const float*)d_in[3];
  const float* W_B  = (const float*)d_in[4];
  const int* parent = (const int*)d_in[5];
  const int* child  = (const int*)d_in[6];
  const int* mask   = (const int*)d_in[7];
  float* out = (float*)d_out;

  const int n_nodes = in_sizes[5];

  unsigned short* wb = (unsigned short*)d_ws;      // [1024][256] bf16 (A,U,V,B rows)
  unsigned short* px = wb + 4*65536;               // [N][1024] bf16

  dim3 gc(32, 4);
  cvt_w<<<gc, 256, 0, stream>>>(W_A, W_U, W_V, W_B, wb);

  gemm_all<<<(n_nodes + 127)/128, 512, 0, stream>>>(prev, wb, px, n_nodes);

  epilogue<<<(n_nodes + 3)/4, 256, 0, stream>>>(px, parent, child, mask, out, n_nodes);
}